// Round 1
// baseline (489.110 us; speedup 1.0000x reference)
//
#include <hip/hip_runtime.h>

#define EPSV 1e-5f

typedef __attribute__((ext_vector_type(8))) short short8v;
typedef __attribute__((ext_vector_type(4))) float f32x4;

static __device__ __forceinline__ unsigned short f2bf(float f) {
  unsigned int u = __float_as_uint(f);
  u += 0x7fff + ((u >> 16) & 1);
  return (unsigned short)(u >> 16);
}
static __device__ __forceinline__ float bf2f(unsigned short h) {
  return __uint_as_float(((unsigned int)h) << 16);
}

// ---------------------------------------------------------------------------
// Prep: conv weights -> Wr[t][cc][co][cil] bf16   (t = dy*3+dx, cc = ci/32)
// ---------------------------------------------------------------------------
__global__ __launch_bounds__(256) void prep_convw_kernel(
    const float* __restrict__ cw, unsigned short* __restrict__ Wr)
{
  int idx = blockIdx.x * 256 + threadIdx.x;
  if (idx >= 9 * 8 * 256 * 32) return;
  int cil = idx & 31;
  int rest = idx >> 5;
  int co = rest & 255;
  int tcc = rest >> 8;
  int cc = tcc & 7;
  int t = tcc >> 3;
  int dy = t / 3, dx = t - dy * 3;
  int ci = cc * 32 + cil;
  Wr[idx] = f2bf(cw[((co * 256 + ci) * 3 + dy) * 3 + dx]);
}

// Prep: transpose wq,wk,wv,wo,rec -> wT[m][ci][co] (f32)
__global__ __launch_bounds__(256) void prep_transpose_kernel(
    const float* __restrict__ wq, const float* __restrict__ wk,
    const float* __restrict__ wv, const float* __restrict__ wo,
    const float* __restrict__ rec, float* __restrict__ wT)
{
  int idx = blockIdx.x * 256 + threadIdx.x;
  if (idx >= 5 * 65536) return;
  int m = idx >> 16;
  int e = idx & 65535;
  int ci = e >> 8, co = e & 255;
  const float* src = (m == 0) ? wq : (m == 1) ? wk : (m == 2) ? wv : (m == 3) ? wo : rec;
  wT[idx] = src[co * 256 + ci];
}

// ---------------------------------------------------------------------------
// Conv 3x3 + bias + BN + SiLU -> feat NHWC bf16.  One block per (b, y).
// MFMA implicit GEMM: M=80 (x), N=256 (co), K = 9 taps * 256 ci.
// ---------------------------------------------------------------------------
__global__ __launch_bounds__(512, 4) void conv_kernel(
    const float* __restrict__ x,
    const float* __restrict__ convb,
    const float* __restrict__ bn1g, const float* __restrict__ bn1b,
    const float* __restrict__ bn1m, const float* __restrict__ bn1v,
    const unsigned short* __restrict__ Wr,
    unsigned short* __restrict__ feat)
{
  const int blk = blockIdx.x;
  const int b = blk / 80, y = blk - b * 80;
  const int tid = threadIdx.x;
  const int wave = tid >> 6, lane = tid & 63;
  const int bq = lane >> 4, r16 = lane & 15;

  __shared__ __align__(16) unsigned short lds[21120];
  unsigned short* in_t = lds;           // [(yy*82+xx)*40 + cil], rows padded to 40
  unsigned short* W_t  = lds + 9840;    // [co*40 + cil]

  f32x4 acc[5][2];
#pragma unroll
  for (int i = 0; i < 5; ++i)
#pragma unroll
    for (int j = 0; j < 2; ++j)
      acc[i][j] = (f32x4){0.f, 0.f, 0.f, 0.f};

  const float* xb = x + (size_t)b * 256 * 6400;

  for (int cc = 0; cc < 8; ++cc) {
    __syncthreads();
    // stage input: rows y-1..y+1 (zero OOB), x -1..80, 32 channels -> bf16
    for (int idx = tid; idx < 96 * 82; idx += 512) {
      int rrow = idx / 82;
      int xx   = idx - rrow * 82;
      int yy   = rrow >> 5;
      int cil  = rrow & 31;
      int gy = y + yy - 1;
      int gx = xx - 1;
      float v = 0.f;
      if ((unsigned)gy < 80u && (unsigned)gx < 80u)
        v = xb[(size_t)(cc * 32 + cil) * 6400 + gy * 80 + gx];
      in_t[(yy * 82 + xx) * 40 + cil] = f2bf(v);
    }
    for (int t = 0; t < 9; ++t) {
      __syncthreads();
      // stage weights for (t, cc): 256 co x 32 ci, contiguous 16KB in Wr
      const unsigned short* wg = Wr + (((size_t)(t * 8 + cc)) << 13);
      for (int i2 = tid; i2 < 1024; i2 += 512) {
        int eo = i2 << 3;
        int co = eo >> 5, cil = eo & 31;
        *(short8v*)&W_t[co * 40 + cil] = *(const short8v*)&wg[eo];
      }
      __syncthreads();
      const int dy = t / 3, dx = t - dy * 3;
      short8v wf0 = *(const short8v*)&W_t[((wave * 2 + 0) * 16 + r16) * 40 + bq * 8];
      short8v wf1 = *(const short8v*)&W_t[((wave * 2 + 1) * 16 + r16) * 40 + bq * 8];
#pragma unroll
      for (int xf = 0; xf < 5; ++xf) {
        int xx = xf * 16 + r16 + dx;
        short8v af = *(const short8v*)&in_t[(dy * 82 + xx) * 40 + bq * 8];
        acc[xf][0] = __builtin_amdgcn_mfma_f32_16x16x32_bf16(af, wf0, acc[xf][0], 0, 0, 0);
        acc[xf][1] = __builtin_amdgcn_mfma_f32_16x16x32_bf16(af, wf1, acc[xf][1], 0, 0, 0);
      }
    }
  }

  // epilogue: bias + BN + SiLU, stage to LDS, coalesced NHWC write
  __syncthreads();
  unsigned short* ep = lds;             // [x*264 + co]
#pragma unroll
  for (int cf = 0; cf < 2; ++cf) {
    int co = wave * 32 + cf * 16 + r16;
    float s  = bn1g[co] / sqrtf(bn1v[co] + EPSV);
    float sh = bn1b[co] - bn1m[co] * s;
    float cb = convb[co];
#pragma unroll
    for (int xf = 0; xf < 5; ++xf) {
#pragma unroll
      for (int r = 0; r < 4; ++r) {
        int xx = xf * 16 + bq * 4 + r;   // D row = 4*(lane>>4)+reg (m89)
        float v = (acc[xf][cf][r] + cb) * s + sh;
        v = v / (1.f + __expf(-v));      // SiLU
        ep[xx * 264 + co] = f2bf(v);
      }
    }
  }
  __syncthreads();
  unsigned short* fout = feat + (size_t)(b * 80 + y) * 80 * 256;
  for (int i2 = tid; i2 < 2560; i2 += 512) {
    int xx = i2 >> 5;
    int coB = (i2 & 31) << 3;
    *(short8v*)&fout[xx * 256 + coB] = *(const short8v*)&ep[xx * 264 + coB];
  }
}

// ---------------------------------------------------------------------------
// roi_align 1x1 (S=4, torchvision semantics). Block per node, thread per ch.
// ---------------------------------------------------------------------------
__global__ __launch_bounds__(256) void roi_kernel(
    const unsigned short* __restrict__ feat,
    const float* __restrict__ boxes,
    float* __restrict__ nodes)
{
  const int n = blockIdx.x;
  const int b = n >> 5;
  const int c = threadIdx.x;
  const float* bx = boxes + n * 4;
  float x1 = bx[0] * 79.f, y1 = bx[1] * 79.f, x2 = bx[2] * 79.f, y2 = bx[3] * 79.f;
  float rw = fmaxf(x2 - x1, 1.f), rh = fmaxf(y2 - y1, 1.f);
  const unsigned short* fb = feat + (size_t)b * 80 * 80 * 256;
  float acc = 0.f;
#pragma unroll
  for (int sy = 0; sy < 4; ++sy) {
    float yy = y1 + (sy + 0.5f) * 0.25f * rh;
#pragma unroll
    for (int sx = 0; sx < 4; ++sx) {
      float xx = x1 + (sx + 0.5f) * 0.25f * rw;
      if (yy < -1.f || yy > 80.f || xx < -1.f || xx > 80.f) continue;
      float yc = fminf(fmaxf(yy, 0.f), 79.f);
      float xc = fminf(fmaxf(xx, 0.f), 79.f);
      float y0 = floorf(yc), x0f = floorf(xc);
      int y0i = (int)y0, x0i = (int)x0f;
      int y1i = min(y0i + 1, 79), x1i = min(x0i + 1, 79);
      float ly = yc - y0, lx = xc - x0f;
      float hy = 1.f - ly, hx = 1.f - lx;
      float v00 = bf2f(fb[((y0i * 80) + x0i) * 256 + c]);
      float v01 = bf2f(fb[((y0i * 80) + x1i) * 256 + c]);
      float v10 = bf2f(fb[((y1i * 80) + x0i) * 256 + c]);
      float v11 = bf2f(fb[((y1i * 80) + x1i) * 256 + c]);
      acc += hy * hx * v00 + hy * lx * v01 + ly * hx * v10 + ly * lx * v11;
    }
  }
  nodes[n * 256 + c] = acc * 0.0625f;
}

// ---------------------------------------------------------------------------
// q,k,v projections. Block handles 8 nodes; thread = output channel.
// ---------------------------------------------------------------------------
__global__ __launch_bounds__(256) void qkv_kernel(
    const float* __restrict__ nodes, const float* __restrict__ wT,
    const float* __restrict__ bq, const float* __restrict__ bk,
    const float* __restrict__ bv,
    float* __restrict__ q, float* __restrict__ k, float* __restrict__ v)
{
  const int blk = blockIdx.x;
  const int co = threadIdx.x;
  __shared__ float nd[8][256];
  for (int i = threadIdx.x; i < 2048; i += 256)
    nd[i >> 8][i & 255] = nodes[blk * 2048 + i];
  __syncthreads();
  float aq[8] = {0,0,0,0,0,0,0,0};
  float ak[8] = {0,0,0,0,0,0,0,0};
  float av[8] = {0,0,0,0,0,0,0,0};
  const float* wqT = wT;
  const float* wkT = wT + 65536;
  const float* wvT = wT + 131072;
  for (int ci = 0; ci < 256; ++ci) {
    float wq_ = wqT[ci * 256 + co];
    float wk_ = wkT[ci * 256 + co];
    float wv_ = wvT[ci * 256 + co];
#pragma unroll
    for (int r = 0; r < 8; ++r) {
      float nv = nd[r][ci];
      aq[r] += nv * wq_;
      ak[r] += nv * wk_;
      av[r] += nv * wv_;
    }
  }
  float bq_ = bq[co], bk_ = bk[co], bv_ = bv[co];
#pragma unroll
  for (int r = 0; r < 8; ++r) {
    int n = blk * 8 + r;
    q[n * 256 + co] = aq[r] + bq_;
    k[n * 256 + co] = ak[r] + bk_;
    v[n * 256 + co] = av[r] + bv_;
  }
}

// ---------------------------------------------------------------------------
// Attention over all 512 nodes + out-proj + residual + LayerNorm.
// Block per query node i.
// ---------------------------------------------------------------------------
__global__ __launch_bounds__(256) void attn_kernel(
    const float* __restrict__ q, const float* __restrict__ k,
    const float* __restrict__ v, const float* __restrict__ nodes,
    const float* __restrict__ woT, const float* __restrict__ bo,
    const float* __restrict__ lng, const float* __restrict__ lnb,
    const float* __restrict__ scale_p, float* __restrict__ enh)
{
  const int i = blockIdx.x;
  const int tid = threadIdx.x;
  const float scale = scale_p[0];
  __shared__ __align__(16) float qs[256];
  __shared__ float sc[512 * 8];
  __shared__ float msgs[256];
  __shared__ float r1[4], r2[4];
  qs[tid] = q[i * 256 + tid];
  __syncthreads();
  {
    const int h = tid & 7, jl = tid >> 3;
    for (int jc = 0; jc < 16; ++jc) {
      int j = jc * 32 + jl;
      const f32x4* kr = (const f32x4*)(k + (size_t)j * 256 + h * 32);
      const f32x4* qr = (const f32x4*)(qs + h * 32);
      float s = 0.f;
#pragma unroll
      for (int d4 = 0; d4 < 8; ++d4) {
        f32x4 kv = kr[d4], qv = qr[d4];
        s += kv.x * qv.x + kv.y * qv.y + kv.z * qv.z + kv.w * qv.w;
      }
      sc[j * 8 + h] = s * scale;
    }
  }
  __syncthreads();
  const int hh = tid >> 5, l32 = tid & 31;
  float mx = -1e30f;
  for (int j = l32; j < 512; j += 32) mx = fmaxf(mx, sc[j * 8 + hh]);
#pragma unroll
  for (int o = 1; o < 32; o <<= 1) mx = fmaxf(mx, __shfl_xor(mx, o, 32));
  float sum = 0.f;
  for (int j = l32; j < 512; j += 32) {
    float e = __expf(sc[j * 8 + hh] - mx);
    sc[j * 8 + hh] = e;
    sum += e;
  }
#pragma unroll
  for (int o = 1; o < 32; o <<= 1) sum += __shfl_xor(sum, o, 32);
  float inv = 1.f / sum;
  __syncthreads();
  {
    const int d = l32;
    float m = 0.f;
    for (int j = 0; j < 512; ++j)
      m += sc[j * 8 + hh] * v[(size_t)j * 256 + hh * 32 + d];
    msgs[hh * 32 + d] = m * inv;
  }
  __syncthreads();
  const int co = tid;
  float yv = nodes[i * 256 + co] + bo[co];
  for (int ci = 0; ci < 256; ++ci)
    yv += msgs[ci] * woT[ci * 256 + co];
  float s1 = yv, s2 = yv * yv;
#pragma unroll
  for (int o = 1; o < 64; o <<= 1) { s1 += __shfl_xor(s1, o); s2 += __shfl_xor(s2, o); }
  if ((tid & 63) == 0) { r1[tid >> 6] = s1; r2[tid >> 6] = s2; }
  __syncthreads();
  float S1 = r1[0] + r1[1] + r1[2] + r1[3];
  float S2 = r2[0] + r2[1] + r2[2] + r2[3];
  float mu = S1 * (1.f / 256.f);
  float var = S2 * (1.f / 256.f) - mu * mu;
  float nrm = (yv - mu) * rsqrtf(var + EPSV);
  enh[i * 256 + co] = nrm * lng[co] + lnb[co];
}

// ---------------------------------------------------------------------------
// Per-batch pooling + rec 1x1 conv + BN2 -> yfin[b][c]. Block per batch.
// ---------------------------------------------------------------------------
__global__ __launch_bounds__(256) void final_kernel(
    const float* __restrict__ enh, const float* __restrict__ recT,
    const float* __restrict__ recb,
    const float* __restrict__ bn2g, const float* __restrict__ bn2b,
    const float* __restrict__ bn2m, const float* __restrict__ bn2v,
    float* __restrict__ yfin)
{
  const int b = blockIdx.x;
  const int tid = threadIdx.x;
  const int wv = tid >> 6, l = tid & 63;
  __shared__ float rm[32], wts[32], wgt[256];
  for (int kk = wv; kk < 32; kk += 4) {
    const float* er = enh + (size_t)(b * 32 + kk) * 256;
    float s = er[l] + er[l + 64] + er[l + 128] + er[l + 192];
#pragma unroll
    for (int o = 1; o < 64; o <<= 1) s += __shfl_xor(s, o);
    if (l == 0) rm[kk] = s * (1.f / 256.f);
  }
  __syncthreads();
  if (tid < 32) {
    float m = rm[tid];
    float mx = m;
#pragma unroll
    for (int o = 1; o < 32; o <<= 1) mx = fmaxf(mx, __shfl_xor(mx, o, 32));
    float e = __expf(m - mx);
    float sm = e;
#pragma unroll
    for (int o = 1; o < 32; o <<= 1) sm += __shfl_xor(sm, o, 32);
    wts[tid] = e / sm;
  }
  __syncthreads();
  float wsum = 0.f;
  for (int kk = 0; kk < 32; ++kk)
    wsum += enh[(size_t)(b * 32 + kk) * 256 + tid] * wts[kk];
  wgt[tid] = wsum;
  __syncthreads();
  const int co = tid;
  float yv = recb[co];
  for (int ci = 0; ci < 256; ++ci)
    yv += wgt[ci] * recT[ci * 256 + co];
  float s = bn2g[co] / sqrtf(bn2v[co] + EPSV);
  yfin[b * 256 + co] = yv * s + (bn2b[co] - bn2m[co] * s);
}

// ---------------------------------------------------------------------------
// out = x + yfin[b][c] broadcast
// ---------------------------------------------------------------------------
__global__ __launch_bounds__(256) void add_kernel(
    const float* __restrict__ x, const float* __restrict__ yfin,
    float* __restrict__ out)
{
  const size_t tot = (size_t)26214400 / 4;
  for (size_t idx = (size_t)blockIdx.x * 256 + threadIdx.x; idx < tot;
       idx += (size_t)gridDim.x * 256) {
    size_t e = idx * 4;
    int bc = (int)(e / 6400);
    f32x4 xv = ((const f32x4*)x)[idx];
    float a = yfin[bc];
    xv.x += a; xv.y += a; xv.z += a; xv.w += a;
    ((f32x4*)out)[idx] = xv;
  }
}

extern "C" void kernel_launch(void* const* d_in, const int* in_sizes, int n_in,
                              void* d_out, int out_size, void* d_ws, size_t ws_size,
                              hipStream_t stream)
{
  const float* x      = (const float*)d_in[0];
  const float* boxes  = (const float*)d_in[1];
  const float* conv_w = (const float*)d_in[2];
  const float* conv_b = (const float*)d_in[3];
  const float* bn1g   = (const float*)d_in[4];
  const float* bn1b   = (const float*)d_in[5];
  const float* bn1m   = (const float*)d_in[6];
  const float* bn1v   = (const float*)d_in[7];
  const float* wq     = (const float*)d_in[8];
  const float* bq     = (const float*)d_in[9];
  const float* wk     = (const float*)d_in[10];
  const float* bkp    = (const float*)d_in[11];
  const float* wv     = (const float*)d_in[12];
  const float* bv     = (const float*)d_in[13];
  const float* scale  = (const float*)d_in[14];
  const float* wo     = (const float*)d_in[15];
  const float* bo     = (const float*)d_in[16];
  const float* lng    = (const float*)d_in[17];
  const float* lnb    = (const float*)d_in[18];
  const float* rec_w  = (const float*)d_in[19];
  const float* rec_b  = (const float*)d_in[20];
  const float* bn2g   = (const float*)d_in[21];
  const float* bn2b   = (const float*)d_in[22];
  const float* bn2m   = (const float*)d_in[23];
  const float* bn2v   = (const float*)d_in[24];
  float* out = (float*)d_out;

  char* ws = (char*)d_ws;
  unsigned short* Wr   = (unsigned short*)(ws);                       // 1,179,648 B
  unsigned short* feat = (unsigned short*)(ws + 1179648);             // 52,428,800 B
  float* wT    = (float*)(ws + 53608448);                             // 1,310,720 B
  float* nodes = (float*)(ws + 54919168);                             // 512 KB each:
  float* qb    = nodes + 131072;
  float* kb    = qb + 131072;
  float* vb    = kb + 131072;
  float* enh   = vb + 131072;
  float* yfin  = enh + 131072;

  hipLaunchKernelGGL(prep_convw_kernel, dim3(2304), dim3(256), 0, stream, conv_w, Wr);
  hipLaunchKernelGGL(prep_transpose_kernel, dim3(1280), dim3(256), 0, stream,
                     wq, wk, wv, wo, rec_w, wT);
  hipLaunchKernelGGL(conv_kernel, dim3(1280), dim3(512), 0, stream,
                     x, conv_b, bn1g, bn1b, bn1m, bn1v, Wr, feat);
  hipLaunchKernelGGL(roi_kernel, dim3(512), dim3(256), 0, stream, feat, boxes, nodes);
  hipLaunchKernelGGL(qkv_kernel, dim3(64), dim3(256), 0, stream,
                     nodes, wT, bq, bkp, bv, qb, kb, vb);
  hipLaunchKernelGGL(attn_kernel, dim3(512), dim3(256), 0, stream,
                     qb, kb, vb, nodes, wT + 3 * 65536, bo, lng, lnb, scale, enh);
  hipLaunchKernelGGL(final_kernel, dim3(16), dim3(256), 0, stream,
                     enh, wT + 4 * 65536, rec_b, bn2g, bn2b, bn2m, bn2v, yfin);
  hipLaunchKernelGGL(add_kernel, dim3(2048), dim3(256), 0, stream, x, yfin, out);
}

// Round 2
// 330.090 us; speedup vs baseline: 1.4817x; 1.4817x over previous
//
#include <hip/hip_runtime.h>

#define EPSV 1e-5f

typedef __attribute__((ext_vector_type(8))) short short8v;
typedef __attribute__((ext_vector_type(4))) float f32x4;

static __device__ __forceinline__ unsigned short f2bf(float f) {
  unsigned int u = __float_as_uint(f);
  u += 0x7fff + ((u >> 16) & 1);
  return (unsigned short)(u >> 16);
}
static __device__ __forceinline__ float bf2f(unsigned short h) {
  return __uint_as_float(((unsigned int)h) << 16);
}

// ---------------------------------------------------------------------------
// Prep: conv weights -> Wr[t][cc][co][cil] bf16   (t = dy*3+dx, cc = ci/32)
// ---------------------------------------------------------------------------
__global__ __launch_bounds__(256) void prep_convw_kernel(
    const float* __restrict__ cw, unsigned short* __restrict__ Wr)
{
  int idx = blockIdx.x * 256 + threadIdx.x;
  if (idx >= 9 * 8 * 256 * 32) return;
  int cil = idx & 31;
  int rest = idx >> 5;
  int co = rest & 255;
  int tcc = rest >> 8;
  int cc = tcc & 7;
  int t = tcc >> 3;
  int dy = t / 3, dx = t - dy * 3;
  int ci = cc * 32 + cil;
  Wr[idx] = f2bf(cw[((co * 256 + ci) * 3 + dy) * 3 + dx]);
}

// Prep: transpose wq,wk,wv,wo,rec -> wT[m][ci][co] (f32)
__global__ __launch_bounds__(256) void prep_transpose_kernel(
    const float* __restrict__ wq, const float* __restrict__ wk,
    const float* __restrict__ wv, const float* __restrict__ wo,
    const float* __restrict__ rec, float* __restrict__ wT)
{
  int idx = blockIdx.x * 256 + threadIdx.x;
  if (idx >= 5 * 65536) return;
  int m = idx >> 16;
  int e = idx & 65535;
  int ci = e >> 8, co = e & 255;
  const float* src = (m == 0) ? wq : (m == 1) ? wk : (m == 2) ? wv : (m == 3) ? wo : rec;
  wT[idx] = src[co * 256 + ci];
}

// ---------------------------------------------------------------------------
// Prep: x NCHW f32 -> xin NHWC bf16 (LDS transpose per (b,y) row)
// ---------------------------------------------------------------------------
__global__ __launch_bounds__(256) void prep_nhwc_kernel(
    const float* __restrict__ x, unsigned short* __restrict__ xin)
{
  int blk = blockIdx.x;
  int b = blk / 80, y = blk - b * 80;
  __shared__ unsigned short t[80 * 257];
  const float* src = x + (size_t)b * 256 * 6400 + y * 80;
  for (int e = threadIdx.x; e < 80 * 256; e += 256) {
    int c = e / 80;
    int px = e - c * 80;
    t[px * 257 + c] = f2bf(src[(size_t)c * 6400 + px]);
  }
  __syncthreads();
  unsigned short* dst = xin + (size_t)blk * 80 * 256;
  for (int e = threadIdx.x; e < 80 * 32; e += 256) {
    int px = e >> 5;
    int c8 = e & 31;
    short8v v;
#pragma unroll
    for (int j = 0; j < 8; ++j) v[j] = t[px * 257 + c8 * 8 + j];
    *(short8v*)&dst[px * 256 + c8 * 8] = v;
  }
}

// ---------------------------------------------------------------------------
// Conv 3x3 + bias + BN + SiLU -> feat NHWC bf16.
// Block per (b, 2 rows). 8 waves = 2(row) x 4(co64). Weights read per-lane
// straight from global (L2); input double-buffered in LDS, XOR-swizzled.
// ---------------------------------------------------------------------------
__global__ __launch_bounds__(512, 2) void conv_kernel(
    const unsigned short* __restrict__ xin,
    const float* __restrict__ convb,
    const float* __restrict__ bn1g, const float* __restrict__ bn1b,
    const float* __restrict__ bn1m, const float* __restrict__ bn1v,
    const unsigned short* __restrict__ Wr,
    unsigned short* __restrict__ feat)
{
  const int blk = blockIdx.x;
  const int b = blk / 40, yp = blk - b * 40;
  const int yb = yp * 2;
  const int tid = threadIdx.x;
  const int wave = tid >> 6, lane = tid & 63;
  const int bq = lane >> 4, r16 = lane & 15;
  const int wm = wave >> 2, wn = wave & 3;

  __shared__ __align__(16) unsigned short lds[21120];
  // input buffers: buf[i] at i*10496 shorts; 1312 slots of 16B each:
  // slot = (row*82 + px)*4 + swz, stores channels chunk = swz ^ (px&3)

  f32x4 acc[5][4];
#pragma unroll
  for (int i = 0; i < 5; ++i)
#pragma unroll
    for (int j = 0; j < 4; ++j)
      acc[i][j] = (f32x4){0.f, 0.f, 0.f, 0.f};

  const int s0 = tid, s1 = tid + 512, s2 = tid + 1024;
  const bool has2 = (tid < 288);

  // staging register load for channel-chunk cc
  auto ld_slot = [&](int s, int cc, short8v& r) {
    int row = s / 328;
    int rem = s - row * 328;
    int px = rem >> 2;
    int swz = rem & 3;
    int chunk = swz ^ (px & 3);
    int gy = yb + row - 1, gx = px - 1;
    if ((unsigned)gy < 80u && (unsigned)gx < 80u)
      r = *(const short8v*)&xin[(((size_t)(b * 80 + gy)) * 80 + gx) * 256 + cc * 32 + chunk * 8];
    else
      r = (short8v){0, 0, 0, 0, 0, 0, 0, 0};
  };

  short8v st0, st1, st2;
  // prologue: stage cc=0 into buf0
  ld_slot(s0, 0, st0);
  ld_slot(s1, 0, st1);
  if (has2) ld_slot(s2, 0, st2);
  *(short8v*)&lds[s0 * 8] = st0;
  *(short8v*)&lds[s1 * 8] = st1;
  if (has2) *(short8v*)&lds[s2 * 8] = st2;
  // preload regs for cc=1
  ld_slot(s0, 1, st0);
  ld_slot(s1, 1, st1);
  if (has2) ld_slot(s2, 1, st2);
  __syncthreads();

  const int wlaneoff = (wn * 64 + r16) * 32 + bq * 8;  // + cf*512 per cf
  // per-lane swizzle terms for dx = 0,1,2 (short offsets)
  int swz8[3];
#pragma unroll
  for (int dx = 0; dx < 3; ++dx) swz8[dx] = (bq ^ ((r16 + dx) & 3)) * 8;

  for (int cc = 0; cc < 8; ++cc) {
    const int cur = cc & 1;
    const int nb = (cur ^ 1) * 10496;
    // write-late: stage regs (data for cc+1) into the other buffer
    if (cc < 7) {
      *(short8v*)&lds[nb + s0 * 8] = st0;
      *(short8v*)&lds[nb + s1 * 8] = st1;
      if (has2) *(short8v*)&lds[nb + s2 * 8] = st2;
    }
    // issue-early: global loads for cc+2
    if (cc < 6) {
      ld_slot(s0, cc + 2, st0);
      ld_slot(s1, cc + 2, st1);
      if (has2) ld_slot(s2, cc + 2, st2);
    }
    const int bufbase = cur * 10496;
#pragma unroll
    for (int t = 0; t < 9; ++t) {
      const int dy = t / 3, dx = t - dy * 3;
      const unsigned short* wg = Wr + (((size_t)(t * 8 + cc)) << 13) + wlaneoff;
      short8v wf0 = *(const short8v*)&wg[0];
      short8v wf1 = *(const short8v*)&wg[512];
      short8v wf2 = *(const short8v*)&wg[1024];
      short8v wf3 = *(const short8v*)&wg[1536];
      const int rowoff = bufbase + ((wm + dy) * 82 + dx + r16) * 32 + swz8[dx];
#pragma unroll
      for (int xf = 0; xf < 5; ++xf) {
        short8v af = *(const short8v*)&lds[rowoff + xf * 512];
        acc[xf][0] = __builtin_amdgcn_mfma_f32_16x16x32_bf16(af, wf0, acc[xf][0], 0, 0, 0);
        acc[xf][1] = __builtin_amdgcn_mfma_f32_16x16x32_bf16(af, wf1, acc[xf][1], 0, 0, 0);
        acc[xf][2] = __builtin_amdgcn_mfma_f32_16x16x32_bf16(af, wf2, acc[xf][2], 0, 0, 0);
        acc[xf][3] = __builtin_amdgcn_mfma_f32_16x16x32_bf16(af, wf3, acc[xf][3], 0, 0, 0);
      }
    }
    __syncthreads();
  }

  // epilogue: bias + BN + SiLU, one output row at a time via LDS
  unsigned short* ep = lds;  // [xx*264 + co], 80*264 = 21120 shorts
#pragma unroll
  for (int rr = 0; rr < 2; ++rr) {
    if (wm == rr) {
#pragma unroll
      for (int cf = 0; cf < 4; ++cf) {
        int co = wn * 64 + cf * 16 + r16;
        float s  = bn1g[co] / sqrtf(bn1v[co] + EPSV);
        float sh = bn1b[co] - bn1m[co] * s;
        float cb = convb[co];
#pragma unroll
        for (int xf = 0; xf < 5; ++xf) {
#pragma unroll
          for (int r = 0; r < 4; ++r) {
            int xx = xf * 16 + bq * 4 + r;  // D row = 4*(lane>>4)+reg (m89)
            float v = (acc[xf][cf][r] + cb) * s + sh;
            v = v / (1.f + __expf(-v));     // SiLU
            ep[xx * 264 + co] = f2bf(v);
          }
        }
      }
    }
    __syncthreads();
    unsigned short* fout = feat + (size_t)((b * 80 + yb + rr) * 80) * 256;
    for (int i2 = tid; i2 < 2560; i2 += 512) {
      int xx = i2 >> 5;
      int c8 = (i2 & 31) << 3;
      *(short8v*)&fout[xx * 256 + c8] = *(const short8v*)&ep[xx * 264 + c8];
    }
    __syncthreads();
  }
}

// ---------------------------------------------------------------------------
// roi_align 1x1 (S=4, torchvision semantics). Block per node, thread per ch.
// ---------------------------------------------------------------------------
__global__ __launch_bounds__(256) void roi_kernel(
    const unsigned short* __restrict__ feat,
    const float* __restrict__ boxes,
    float* __restrict__ nodes)
{
  const int n = blockIdx.x;
  const int b = n >> 5;
  const int c = threadIdx.x;
  const float* bx = boxes + n * 4;
  float x1 = bx[0] * 79.f, y1 = bx[1] * 79.f, x2 = bx[2] * 79.f, y2 = bx[3] * 79.f;
  float rw = fmaxf(x2 - x1, 1.f), rh = fmaxf(y2 - y1, 1.f);
  const unsigned short* fb = feat + (size_t)b * 80 * 80 * 256;
  float acc = 0.f;
#pragma unroll
  for (int sy = 0; sy < 4; ++sy) {
    float yy = y1 + (sy + 0.5f) * 0.25f * rh;
#pragma unroll
    for (int sx = 0; sx < 4; ++sx) {
      float xx = x1 + (sx + 0.5f) * 0.25f * rw;
      if (yy < -1.f || yy > 80.f || xx < -1.f || xx > 80.f) continue;
      float yc = fminf(fmaxf(yy, 0.f), 79.f);
      float xc = fminf(fmaxf(xx, 0.f), 79.f);
      float y0 = floorf(yc), x0f = floorf(xc);
      int y0i = (int)y0, x0i = (int)x0f;
      int y1i = min(y0i + 1, 79), x1i = min(x0i + 1, 79);
      float ly = yc - y0, lx = xc - x0f;
      float hy = 1.f - ly, hx = 1.f - lx;
      float v00 = bf2f(fb[((y0i * 80) + x0i) * 256 + c]);
      float v01 = bf2f(fb[((y0i * 80) + x1i) * 256 + c]);
      float v10 = bf2f(fb[((y1i * 80) + x0i) * 256 + c]);
      float v11 = bf2f(fb[((y1i * 80) + x1i) * 256 + c]);
      acc += hy * hx * v00 + hy * lx * v01 + ly * hx * v10 + ly * lx * v11;
    }
  }
  nodes[n * 256 + c] = acc * 0.0625f;
}

// ---------------------------------------------------------------------------
// q,k,v projections. Block handles 8 nodes; thread = output channel.
// ---------------------------------------------------------------------------
__global__ __launch_bounds__(256) void qkv_kernel(
    const float* __restrict__ nodes, const float* __restrict__ wT,
    const float* __restrict__ bq, const float* __restrict__ bk,
    const float* __restrict__ bv,
    float* __restrict__ q, float* __restrict__ k, float* __restrict__ v)
{
  const int blk = blockIdx.x;
  const int co = threadIdx.x;
  __shared__ float nd[8][256];
  for (int i = threadIdx.x; i < 2048; i += 256)
    nd[i >> 8][i & 255] = nodes[blk * 2048 + i];
  __syncthreads();
  float aq[8] = {0,0,0,0,0,0,0,0};
  float ak[8] = {0,0,0,0,0,0,0,0};
  float av[8] = {0,0,0,0,0,0,0,0};
  const float* wqT = wT;
  const float* wkT = wT + 65536;
  const float* wvT = wT + 131072;
  for (int ci = 0; ci < 256; ++ci) {
    float wq_ = wqT[ci * 256 + co];
    float wk_ = wkT[ci * 256 + co];
    float wv_ = wvT[ci * 256 + co];
#pragma unroll
    for (int r = 0; r < 8; ++r) {
      float nv = nd[r][ci];
      aq[r] += nv * wq_;
      ak[r] += nv * wk_;
      av[r] += nv * wv_;
    }
  }
  float bq_ = bq[co], bk_ = bk[co], bv_ = bv[co];
#pragma unroll
  for (int r = 0; r < 8; ++r) {
    int n = blk * 8 + r;
    q[n * 256 + co] = aq[r] + bq_;
    k[n * 256 + co] = ak[r] + bk_;
    v[n * 256 + co] = av[r] + bv_;
  }
}

// ---------------------------------------------------------------------------
// Attention over all 512 nodes + out-proj + residual + LayerNorm.
// Block per query node i.
// ---------------------------------------------------------------------------
__global__ __launch_bounds__(256) void attn_kernel(
    const float* __restrict__ q, const float* __restrict__ k,
    const float* __restrict__ v, const float* __restrict__ nodes,
    const float* __restrict__ woT, const float* __restrict__ bo,
    const float* __restrict__ lng, const float* __restrict__ lnb,
    const float* __restrict__ scale_p, float* __restrict__ enh)
{
  const int i = blockIdx.x;
  const int tid = threadIdx.x;
  const float scale = scale_p[0];
  __shared__ __align__(16) float qs[256];
  __shared__ float sc[512 * 8];
  __shared__ float msgs[256];
  __shared__ float r1[4], r2[4];
  qs[tid] = q[i * 256 + tid];
  __syncthreads();
  {
    const int h = tid & 7, jl = tid >> 3;
    for (int jc = 0; jc < 16; ++jc) {
      int j = jc * 32 + jl;
      const f32x4* kr = (const f32x4*)(k + (size_t)j * 256 + h * 32);
      const f32x4* qr = (const f32x4*)(qs + h * 32);
      float s = 0.f;
#pragma unroll
      for (int d4 = 0; d4 < 8; ++d4) {
        f32x4 kv = kr[d4], qv = qr[d4];
        s += kv.x * qv.x + kv.y * qv.y + kv.z * qv.z + kv.w * qv.w;
      }
      sc[j * 8 + h] = s * scale;
    }
  }
  __syncthreads();
  const int hh = tid >> 5, l32 = tid & 31;
  float mx = -1e30f;
  for (int j = l32; j < 512; j += 32) mx = fmaxf(mx, sc[j * 8 + hh]);
#pragma unroll
  for (int o = 1; o < 32; o <<= 1) mx = fmaxf(mx, __shfl_xor(mx, o, 32));
  float sum = 0.f;
  for (int j = l32; j < 512; j += 32) {
    float e = __expf(sc[j * 8 + hh] - mx);
    sc[j * 8 + hh] = e;
    sum += e;
  }
#pragma unroll
  for (int o = 1; o < 32; o <<= 1) sum += __shfl_xor(sum, o, 32);
  float inv = 1.f / sum;
  __syncthreads();
  {
    const int d = l32;
    float m = 0.f;
    for (int j = 0; j < 512; ++j)
      m += sc[j * 8 + hh] * v[(size_t)j * 256 + hh * 32 + d];
    msgs[hh * 32 + d] = m * inv;
  }
  __syncthreads();
  const int co = tid;
  float yv = nodes[i * 256 + co] + bo[co];
  for (int ci = 0; ci < 256; ++ci)
    yv += msgs[ci] * woT[ci * 256 + co];
  float s1 = yv, s2 = yv * yv;
#pragma unroll
  for (int o = 1; o < 64; o <<= 1) { s1 += __shfl_xor(s1, o); s2 += __shfl_xor(s2, o); }
  if ((tid & 63) == 0) { r1[tid >> 6] = s1; r2[tid >> 6] = s2; }
  __syncthreads();
  float S1 = r1[0] + r1[1] + r1[2] + r1[3];
  float S2 = r2[0] + r2[1] + r2[2] + r2[3];
  float mu = S1 * (1.f / 256.f);
  float var = S2 * (1.f / 256.f) - mu * mu;
  float nrm = (yv - mu) * rsqrtf(var + EPSV);
  enh[i * 256 + co] = nrm * lng[co] + lnb[co];
}

// ---------------------------------------------------------------------------
// Per-batch pooling + rec 1x1 conv + BN2 -> yfin[b][c]. Block per batch.
// ---------------------------------------------------------------------------
__global__ __launch_bounds__(256) void final_kernel(
    const float* __restrict__ enh, const float* __restrict__ recT,
    const float* __restrict__ recb,
    const float* __restrict__ bn2g, const float* __restrict__ bn2b,
    const float* __restrict__ bn2m, const float* __restrict__ bn2v,
    float* __restrict__ yfin)
{
  const int b = blockIdx.x;
  const int tid = threadIdx.x;
  const int wv = tid >> 6, l = tid & 63;
  __shared__ float rm[32], wts[32], wgt[256];
  for (int kk = wv; kk < 32; kk += 4) {
    const float* er = enh + (size_t)(b * 32 + kk) * 256;
    float s = er[l] + er[l + 64] + er[l + 128] + er[l + 192];
#pragma unroll
    for (int o = 1; o < 64; o <<= 1) s += __shfl_xor(s, o);
    if (l == 0) rm[kk] = s * (1.f / 256.f);
  }
  __syncthreads();
  if (tid < 32) {
    float m = rm[tid];
    float mx = m;
#pragma unroll
    for (int o = 1; o < 32; o <<= 1) mx = fmaxf(mx, __shfl_xor(mx, o, 32));
    float e = __expf(m - mx);
    float sm = e;
#pragma unroll
    for (int o = 1; o < 32; o <<= 1) sm += __shfl_xor(sm, o, 32);
    wts[tid] = e / sm;
  }
  __syncthreads();
  float wsum = 0.f;
  for (int kk = 0; kk < 32; ++kk)
    wsum += enh[(size_t)(b * 32 + kk) * 256 + tid] * wts[kk];
  wgt[tid] = wsum;
  __syncthreads();
  const int co = tid;
  float yv = recb[co];
  for (int ci = 0; ci < 256; ++ci)
    yv += wgt[ci] * recT[ci * 256 + co];
  float s = bn2g[co] / sqrtf(bn2v[co] + EPSV);
  yfin[b * 256 + co] = yv * s + (bn2b[co] - bn2m[co] * s);
}

// ---------------------------------------------------------------------------
// out = x + yfin[b][c] broadcast
// ---------------------------------------------------------------------------
__global__ __launch_bounds__(256) void add_kernel(
    const float* __restrict__ x, const float* __restrict__ yfin,
    float* __restrict__ out)
{
  const size_t tot = (size_t)26214400 / 4;
  for (size_t idx = (size_t)blockIdx.x * 256 + threadIdx.x; idx < tot;
       idx += (size_t)gridDim.x * 256) {
    size_t e = idx * 4;
    int bc = (int)(e / 6400);
    f32x4 xv = ((const f32x4*)x)[idx];
    float a = yfin[bc];
    xv.x += a; xv.y += a; xv.z += a; xv.w += a;
    ((f32x4*)out)[idx] = xv;
  }
}

extern "C" void kernel_launch(void* const* d_in, const int* in_sizes, int n_in,
                              void* d_out, int out_size, void* d_ws, size_t ws_size,
                              hipStream_t stream)
{
  const float* x      = (const float*)d_in[0];
  const float* boxes  = (const float*)d_in[1];
  const float* conv_w = (const float*)d_in[2];
  const float* conv_b = (const float*)d_in[3];
  const float* bn1g   = (const float*)d_in[4];
  const float* bn1b   = (const float*)d_in[5];
  const float* bn1m   = (const float*)d_in[6];
  const float* bn1v   = (const float*)d_in[7];
  const float* wq     = (const float*)d_in[8];
  const float* bq     = (const float*)d_in[9];
  const float* wk     = (const float*)d_in[10];
  const float* bkp    = (const float*)d_in[11];
  const float* wv     = (const float*)d_in[12];
  const float* bv     = (const float*)d_in[13];
  const float* scale  = (const float*)d_in[14];
  const float* wo     = (const float*)d_in[15];
  const float* bo     = (const float*)d_in[16];
  const float* lng    = (const float*)d_in[17];
  const float* lnb    = (const float*)d_in[18];
  const float* rec_w  = (const float*)d_in[19];
  const float* rec_b  = (const float*)d_in[20];
  const float* bn2g   = (const float*)d_in[21];
  const float* bn2b   = (const float*)d_in[22];
  const float* bn2m   = (const float*)d_in[23];
  const float* bn2v   = (const float*)d_in[24];
  float* out = (float*)d_out;

  char* ws = (char*)d_ws;
  unsigned short* Wr   = (unsigned short*)(ws);                       // 1,179,648 B
  unsigned short* feat = (unsigned short*)(ws + 1179648);             // 52,428,800 B
  float* wT    = (float*)(ws + 53608448);                             // 1,310,720 B
  float* nodes = (float*)(ws + 54919168);
  float* qb    = nodes + 131072;
  float* kb    = qb + 131072;
  float* vb    = kb + 131072;
  float* enh   = vb + 131072;
  float* yfin  = enh + 131072;

  // xin (NHWC bf16, 52.4 MB) lives in d_out scratch — fully consumed by conv
  // before add_kernel overwrites d_out at the end. Deterministic each call.
  unsigned short* xin = (unsigned short*)d_out;

  hipLaunchKernelGGL(prep_convw_kernel, dim3(2304), dim3(256), 0, stream, conv_w, Wr);
  hipLaunchKernelGGL(prep_transpose_kernel, dim3(1280), dim3(256), 0, stream,
                     wq, wk, wv, wo, rec_w, wT);
  hipLaunchKernelGGL(prep_nhwc_kernel, dim3(1280), dim3(256), 0, stream, x, xin);
  hipLaunchKernelGGL(conv_kernel, dim3(640), dim3(512), 0, stream,
                     xin, conv_b, bn1g, bn1b, bn1m, bn1v, Wr, feat);
  hipLaunchKernelGGL(roi_kernel, dim3(512), dim3(256), 0, stream, feat, boxes, nodes);
  hipLaunchKernelGGL(qkv_kernel, dim3(64), dim3(256), 0, stream,
                     nodes, wT, bq, bkp, bv, qb, kb, vb);
  hipLaunchKernelGGL(attn_kernel, dim3(512), dim3(256), 0, stream,
                     qb, kb, vb, nodes, wT + 3 * 65536, bo, lng, lnb, scale, enh);
  hipLaunchKernelGGL(final_kernel, dim3(16), dim3(256), 0, stream,
                     enh, wT + 4 * 65536, rec_b, bn2g, bn2b, bn2m, bn2v, yfin);
  hipLaunchKernelGGL(add_kernel, dim3(2048), dim3(256), 0, stream, x, yfin, out);
}